// Round 8
// baseline (315.487 us; speedup 1.0000x reference)
//
#include <hip/hip_runtime.h>
#include <hip/hip_bf16.h>
#include <cstdint>

#define DEV __device__ __forceinline__

typedef __attribute__((ext_vector_type(8))) __bf16 bf16x8;
typedef __attribute__((ext_vector_type(4))) float f32x4;

DEV ushort f2bf(float f){
  uint32_t u = __builtin_bit_cast(uint32_t, f);
  u += 0x7fffu + ((u >> 16) & 1u);   // RNE
  return (ushort)(u >> 16);
}

DEV void gll16(const void* g, void* l){
  __builtin_amdgcn_global_load_lds((const __attribute__((address_space(1))) void*)g,
                                   (__attribute__((address_space(3))) void*)l, 16, 0, 0);
}

// ---------------------------------------------------------------------------
// 256x128 tile GEMM, C[M,N] = A[M,K] @ Bt[N,K]^T, bf16 in, f32 acc.
// 256 threads = 4 waves (2M x 2N), per-wave 128x64 output, K-slot = 32.
// ~210 VGPR/thread + 48 KiB LDS -> TWO blocks/CU co-resident (16 waves):
// inter-block TLP hides staging latency and barrier dead-time (m97 regime).
// LDS: 2-slot ring, XOR-swizzled (2-way = free, 0 conflicts measured).
// Schedule: minimal 2-phase atom per slot (T3 minimum): STAGE(t+1) issued
// FIRST, then 12 ds_reads + 32 MFMA, one vmcnt(0)+barrier per slot.
// Block mapping: XCD-contiguous chunks + 4x4 supertiles for L2 working set.
// MODE 0: C_bf16 = acc + bias[col]; bn>=16 writes V transposed to VTout
// MODE 1: C_bf16 = exp(acc*scale), f32 partial row sums (scores)
// MODE 2: C_f32  = acc / denom[row], denom computed in-block from partials
// ---------------------------------------------------------------------------
template<int MODE>
__global__ __launch_bounds__(256, 2) void gemm256(
    const ushort* __restrict__ A, const ushort* __restrict__ Bt,
    const float* __restrict__ bias,
    ushort* __restrict__ Cb, float* __restrict__ Cf, ushort* __restrict__ VTout,
    int gm, int gn, int K, int lda, int ldb, int ldc,
    size_t sA, size_t sB, size_t sC,
    float scale, float* __restrict__ partial, const int* __restrict__ alen,
    int Mrows, int Lpad)
{
  __shared__ __align__(16) ushort As[2][128][64];   // 256 rows x 32 k (2 rows/LDS-row)
  __shared__ __align__(16) ushort Bs[2][64][64];    // 128 rows x 32 k
  __shared__ float dnls[256];

  const int tid  = threadIdx.x;
  const int lane = tid & 63, wid = tid >> 6;
  const int wm = wid >> 1, wn = wid & 1;
  const int lr = lane & 15, fq = lane >> 4;
  const int lrh = lr >> 1;
  const int lo2 = ((lane & 1) << 2) | fq;

  // XCD-aware swizzle + 4x4 supertile (all grids %8==0, gm,gn %4==0)
  const int nwg = gridDim.x;
  const int per = nwg >> 3;
  const int id  = blockIdx.x;
  const int swz = (id & 7) * per + (id >> 3);
  const int gmn = gm * gn;
  const int bz  = swz / gmn;
  const int rr  = swz - bz * gmn;
  const int q4  = rr >> 4, w4 = rr & 15;
  const int nsm = gm >> 2;
  const int stm = q4 % nsm, stn = q4 / nsm;
  const int bm  = (stm << 2) + (w4 & 3);
  const int bn  = (stn << 2) + (w4 >> 2);

  const ushort* Ab = A  + (size_t)bz * sA + (size_t)bm * 256 * (size_t)lda;
  const ushort* Bb = Bt + (size_t)bz * sB + (size_t)bn * 128 * (size_t)ldb;
  const int NT = K >> 5;

  // content swizzle: LDS[R][ci] holds G[2R + (u>>2)][kchunk u&3], u = ci^(R&7)
  auto srcOff = [&](int c, int ld)->size_t{
    int R = c >> 3, ci = c & 7, u = ci ^ (R & 7);
    return (size_t)(2*R + (u >> 2)) * (size_t)(ld*2) + (size_t)((u & 3) << 4);
  };
  const char* srcA[4]; const char* srcB[2];
#pragma unroll
  for (int q = 0; q < 4; ++q) srcA[q] = (const char*)Ab + srcOff(q*256 + tid, lda);
#pragma unroll
  for (int q = 0; q < 2; ++q) srcB[q] = (const char*)Bb + srcOff(q*256 + tid, ldb);
  char* AsB = (char*)As;
  char* BsB = (char*)Bs;
  const int dstw = (wid << 6) * 16;   // wave-uniform; HW adds lane*16

  auto stage = [&](int t){
    const int sa = (t & 1) << 14;     // A slot * 16384 B
    const int sb = (t & 1) << 13;     // B slot * 8192 B
    const size_t kb = (size_t)t << 6;
#pragma unroll
    for (int q = 0; q < 4; ++q)
      gll16(srcA[q] + kb, AsB + sa + q*4096 + dstw);
#pragma unroll
    for (int q = 0; q < 2; ++q)
      gll16(srcB[q] + kb, BsB + sb + q*4096 + dstw);
  };

  f32x4 acc[8][4];
  const f32x4 z = {0.f, 0.f, 0.f, 0.f};
#pragma unroll
  for (int m = 0; m < 8; ++m)
#pragma unroll
    for (int n = 0; n < 4; ++n) acc[m][n] = z;

  const int cio  = (lo2 ^ lrh) << 3;
  const int aoff = (wm*64 + lrh)*64 + cio;   // A: wm*128 rows /2
  const int boff = (wn*32 + lrh)*64 + cio;   // B: wn*64 rows /2

  stage(0);
  asm volatile("s_waitcnt vmcnt(0)" ::: "memory");
  __builtin_amdgcn_s_barrier();

  for (int t = 0; t < NT; ++t){
    const int s = t & 1;
    const ushort* Asl = (const ushort*)As + (size_t)s*8192;
    const ushort* Bsl = (const ushort*)Bs + (size_t)s*4096;

    if (t + 1 < NT) stage(t + 1);     // issue STAGE first (other LDS buffer)

    bf16x8 bfv[4], af[8];
#pragma unroll
    for (int n = 0; n < 4; ++n)
      bfv[n] = *(const bf16x8*)&Bsl[boff + n*512];
#pragma unroll
    for (int m = 0; m < 8; ++m)
      af[m] = *(const bf16x8*)&Asl[aoff + m*512];

    __builtin_amdgcn_s_setprio(1);
#pragma unroll
    for (int m = 0; m < 8; ++m)
#pragma unroll
      for (int n = 0; n < 4; ++n)
        acc[m][n] = __builtin_amdgcn_mfma_f32_16x16x32_bf16(af[m], bfv[n], acc[m][n], 0, 0, 0);
    __builtin_amdgcn_s_setprio(0);

    if (t + 1 < NT){
      asm volatile("s_waitcnt vmcnt(0)" ::: "memory");  // slot t+1 landed (mine)
      __builtin_amdgcn_s_barrier();                     // landed for all waves
    }
  }

  // ---------------- epilogue ----------------
  const int rbase = bm*256 + wm*128 + fq*4;
  const int cbase = bn*128 + wn*64 + lr;

  if (MODE == 0){
    if (bn >= 16){
      // V block: write transposed, VT[b][dv][l], ushort4 over l
#pragma unroll
      for (int m = 0; m < 8; ++m){
        int r0 = rbase + m*16;
        int b = r0 >> 11, l = r0 & 2047;
        ushort* vb = VTout + (size_t)b * 1024 * 2048;
#pragma unroll
        for (int n = 0; n < 4; ++n){
          int c = cbase + n*16;
          float bvv = bias[c];
          ushort4 u4;
          u4.x = f2bf(acc[m][n][0] + bvv);
          u4.y = f2bf(acc[m][n][1] + bvv);
          u4.z = f2bf(acc[m][n][2] + bvv);
          u4.w = f2bf(acc[m][n][3] + bvv);
          *(ushort4*)&vb[(size_t)(c - 2048)*2048 + l] = u4;
        }
      }
    } else {
      ushort* dst = Cb + (size_t)bz * sC;
#pragma unroll
      for (int m = 0; m < 8; ++m){
        int r0 = rbase + m*16;
#pragma unroll
        for (int n = 0; n < 4; ++n){
          int c = cbase + n*16;
          float bvv = bias[c];
#pragma unroll
          for (int i = 0; i < 4; ++i)
            dst[(size_t)(r0 + i)*ldc + c] = f2bf(acc[m][n][i] + bvv);
        }
      }
    }
  } else if (MODE == 1){
    ushort* dst = Cb + (size_t)bz * sC;
#pragma unroll
    for (int m = 0; m < 8; ++m){
      int r0 = rbase + m*16;
#pragma unroll
      for (int i = 0; i < 4; ++i){
        int r = r0 + i;
        float rs = 0.f;
#pragma unroll
        for (int n = 0; n < 4; ++n){
          float v = __expf(acc[m][n][i] * scale);
          dst[(size_t)r*ldc + cbase + n*16] = f2bf(v);
          rs += v;            // f32 sum from f32 exp values (NOT bf16-rounded)
        }
        rs += __shfl_xor(rs, 1);
        rs += __shfl_xor(rs, 2);
        rs += __shfl_xor(rs, 4);
        rs += __shfl_xor(rs, 8);
        if (lr == 0)
          partial[((size_t)bz*Mrows + r)*32 + (bn*2 + wn)] = rs;  // single writer
      }
    }
  } else {
    // denom for this block's 256 rows (deterministic: fixed-order f32 sum)
    {
      int r = bm*256 + tid;
      const float* p = partial + ((size_t)bz*Mrows + r)*32;
      float ssum = 0.f;
#pragma unroll
      for (int j = 0; j < 32; ++j) ssum += p[j];
      dnls[tid] = ssum - (float)(Lpad - alen[bz]);
    }
    __syncthreads();
    float* dst = Cf + (size_t)bz * sC;
#pragma unroll
    for (int m = 0; m < 8; ++m){
      int r0 = rbase + m*16;
#pragma unroll
      for (int i = 0; i < 4; ++i){
        int r = r0 + i;
        float inv = 1.0f / dnls[r - bm*256];
#pragma unroll
        for (int n = 0; n < 4; ++n)
          dst[(size_t)r*ldc + cbase + n*16] = acc[m][n][i] * inv;
      }
    }
  }
}

// ---------------------------------------------------------------------------

__global__ void cvt_f32_bf16(const float* __restrict__ in, ushort* __restrict__ out, long n4){
  long i = (long)blockIdx.x*blockDim.x + threadIdx.x;
  if (i >= n4) return;
  float4 f = ((const float4*)in)[i];
  ushort4 u;
  u.x = f2bf(f.x); u.y = f2bf(f.y); u.z = f2bf(f.z); u.w = f2bf(f.w);
  ((ushort4*)out)[i] = u;
}

// merged: out[z][C,R] = in_z[R,C]^T with f32->bf16 convert. block (32,8), z<3
__global__ __launch_bounds__(256) void transpose_w3(
    const float* __restrict__ Wq, const float* __restrict__ Wk,
    const float* __restrict__ Wv, ushort* __restrict__ out, int R, int C){
  __shared__ ushort t[32][33];
  int zz = blockIdx.z;
  const float* in = (zz == 0) ? Wq : (zz == 1 ? Wk : Wv);
  ushort* o = out + (size_t)zz * R * C;
  int tx = threadIdx.x, ty = threadIdx.y;
  int c0 = blockIdx.x*32, r0 = blockIdx.y*32;
#pragma unroll
  for (int i = 0; i < 4; i++)
    t[ty + i*8][tx] = f2bf(in[(size_t)(r0 + ty + i*8)*C + c0 + tx]);
  __syncthreads();
#pragma unroll
  for (int i = 0; i < 4; i++)
    o[(size_t)(c0 + ty + i*8)*R + r0 + tx] = t[tx][ty + i*8];
}

__global__ void pack_bias(const float* __restrict__ q, const float* __restrict__ k,
                          const float* __restrict__ v, float* __restrict__ o){
  int i = blockIdx.x*blockDim.x + threadIdx.x;   // 3072
  o[i] = (i < 1024) ? q[i] : (i < 2048 ? k[i-1024] : v[i-2048]);
}

// ---------------------------------------------------------------------------

extern "C" void kernel_launch(void* const* d_in, const int* in_sizes, int n_in,
                              void* d_out, int out_size, void* d_ws, size_t ws_size,
                              hipStream_t stream){
  const int B = 8, L = 2048, D = 1024, DK = 1024, DV = 1024;
  const float scale = 0.03125f;  // 1/sqrt(1024)

  const float* x  = (const float*)d_in[0];
  const int* alen = (const int*)d_in[1];
  const float* Wq = (const float*)d_in[2];
  const float* bq = (const float*)d_in[3];
  const float* Wk = (const float*)d_in[4];
  const float* bk = (const float*)d_in[5];
  const float* Wv = (const float*)d_in[6];
  const float* bv = (const float*)d_in[7];
  float* out = (float*)d_out;

  char* ws = (char*)d_ws;
  size_t off = 0;
  auto alloc = [&](size_t bytes) -> void* {
    void* p = ws + off;
    off += (bytes + 255) & ~(size_t)255;
    return p;
  };
  ushort* xb     = (ushort*)alloc((size_t)B*L*D*2);        // 32 MB
  ushort* wqkvT  = (ushort*)alloc((size_t)3*DK*D*2);       // 6 MB
  float*  bqkv   = (float*)alloc((size_t)3*DK*4);
  ushort* QK     = (ushort*)alloc((size_t)B*L*2*DK*2);     // 67 MB (Q|K packed rows)
  ushort* VTb    = (ushort*)alloc((size_t)B*DV*L*2);       // 32 MB (V transposed)
  ushort* S      = (ushort*)alloc((size_t)B*L*L*2);        // 64 MB
  float* partial = (float*)alloc((size_t)B*L*32*4);        // 2 MB
  if (off > ws_size) return;

  // 1. x -> bf16
  long n4 = (long)B*L*D/4;
  cvt_f32_bf16<<<dim3((unsigned)((n4 + 255)/256)), 256, 0, stream>>>(x, xb, n4);

  // 2. packed W^T bf16 [3072][1024] (one launch) + packed bias
  transpose_w3<<<dim3(DK/32, D/32, 3), dim3(32, 8), 0, stream>>>(Wq, Wk, Wv, wqkvT, D, DK);
  pack_bias<<<dim3(12), 256, 0, stream>>>(bq, bk, bv, bqkv);

  // 3. fused QKV projection: Q,K -> QK[B*L, 2048]; V -> VTb transposed
  gemm256<0><<<dim3(64*24), 256, 0, stream>>>(
      xb, wqkvT, bqkv, QK, nullptr, VTb, 64, 24, D, D, D, 2*DK,
      0, 0, 0, 0.f, nullptr, nullptr, 0, 0);

  // 4. scores: S = exp(scale * Q @ K^T), f32 partial row sums
  gemm256<1><<<dim3(8*16*8), 256, 0, stream>>>(
      QK /*Q*/, QK + DK /*K*/, nullptr, S, nullptr, nullptr, 8, 16, DK,
      2*DK, 2*DK, L,
      (size_t)L*2*DK, (size_t)L*2*DK, (size_t)L*L, scale, partial, nullptr, L, 0);

  // 5. out = (S @ V) / denom   (denom computed in-block from partials)
  gemm256<2><<<dim3(8*8*8), 256, 0, stream>>>(
      S, VTb, nullptr, nullptr, out, nullptr, 8, 8, L, L, L, DV,
      (size_t)L*L, (size_t)DV*L, (size_t)L*DV, 1.f, partial, alen, L, L);
}

// Round 9
// 291.553 us; speedup vs baseline: 1.0821x; 1.0821x over previous
//
#include <hip/hip_runtime.h>
#include <hip/hip_bf16.h>
#include <cstdint>

#define DEV __device__ __forceinline__

typedef __attribute__((ext_vector_type(8))) __bf16 bf16x8;
typedef __attribute__((ext_vector_type(4))) float f32x4;

DEV ushort f2bf(float f){
  uint32_t u = __builtin_bit_cast(uint32_t, f);
  u += 0x7fffu + ((u >> 16) & 1u);   // RNE
  return (ushort)(u >> 16);
}

DEV void gll16(const void* g, void* l){
  __builtin_amdgcn_global_load_lds((const __attribute__((address_space(1))) void*)g,
                                   (__attribute__((address_space(3))) void*)l, 16, 0, 0);
}

// ---------------------------------------------------------------------------
// 256x256 tile GEMM, C[M,N] = A[M,K] @ Bt[N,K]^T, bf16 in, f32 acc.
// 512 threads = 8 waves (2 M x 4 N), per-wave 128x64 output, K-slot = 32.
// LDS: 4-slot ring per matrix (128 KiB), XOR-swizzled (2-way = free, 0 confl).
// Schedule (champion, r6): 2 lockstep phases per slot, prefetch depth 2,
// tail vmcnt(4) counted (never drains mid-loop). No lgkm pins (r6: null).
// Block mapping: XCD-contiguous chunks + 4x4 supertiles for L2 working set.
// Occupancy is register-bound at 8 waves/CU (r8 lesson) — geometry can't help.
// MODE 0: C_bf16 = acc + bias[col]; bn>=8 writes V transposed to VTout
// MODE 1: C_bf16 = exp(acc*scale), f32 partial row sums (scores)
// MODE 2: C_f32  = acc / denom[row], denom computed in-block from partials
// ---------------------------------------------------------------------------
template<int MODE>
__global__ __launch_bounds__(512, 2) void gemm256(
    const ushort* __restrict__ A, const ushort* __restrict__ Bt,
    const float* __restrict__ bias,
    ushort* __restrict__ Cb, float* __restrict__ Cf, ushort* __restrict__ VTout,
    int gm, int gn, int K, int lda, int ldb, int ldc,
    size_t sA, size_t sB, size_t sC,
    float scale, float* __restrict__ partial, const int* __restrict__ alen,
    int Mrows, int nch)
{
  __shared__ __align__(16) ushort As[4][128][64];
  __shared__ __align__(16) ushort Bs[4][128][64];
  __shared__ float dnls[256];

  const int tid  = threadIdx.x;
  const int lane = tid & 63, wid = tid >> 6;
  const int wm = wid >> 2, wn = wid & 3;
  const int lr = lane & 15, fq = lane >> 4;
  const int lrh = lr >> 1;
  const int lo2 = ((lane & 1) << 2) | fq;

  // XCD-aware block swizzle + 4x4 supertile (all grids %8==0, gm,gn %4==0):
  // 16 co-resident blocks share 4 A-panels + 4 B-panels (~4 MB ~= XCD L2).
  const int nwg = gridDim.x;
  const int per = nwg >> 3;
  const int id  = blockIdx.x;
  const int swz = (id & 7) * per + (id >> 3);
  const int gmn = gm * gn;
  const int bz  = swz / gmn;
  const int rr  = swz - bz * gmn;
  const int q4  = rr >> 4, w4 = rr & 15;
  const int nsm = gm >> 2;
  const int stm = q4 % nsm, stn = q4 / nsm;
  const int bm  = (stm << 2) + (w4 & 3);
  const int bn  = (stn << 2) + (w4 >> 2);

  const ushort* Ab = A  + (size_t)bz * sA + (size_t)bm * 256 * (size_t)lda;
  const ushort* Bb = Bt + (size_t)bz * sB + (size_t)bn * 256 * (size_t)ldb;
  const int NT = K >> 5;   // K-slots of 32

  // ---- hoisted stage addressing ----
  // chunk c (16B): LDS linear dest c*16 within slot.
  // content swizzle: LDS[R][ci] holds G[2R + (u>>2)][kchunk u&3], u = ci^(R&7).
  auto srcOff = [&](int c, int ld)->size_t{
    int R = c >> 3, ci = c & 7, u = ci ^ (R & 7);
    return (size_t)(2*R + (u >> 2)) * (size_t)(ld*2) + (size_t)((u & 3) << 4);
  };
  const char* srcA0 = (const char*)Ab + srcOff(tid,       lda);
  const char* srcA1 = (const char*)Ab + srcOff(512 + tid, lda);
  const char* srcB0 = (const char*)Bb + srcOff(tid,       ldb);
  const char* srcB1 = (const char*)Bb + srcOff(512 + tid, ldb);
  char* AsB = (char*)As;
  char* BsB = (char*)Bs;
  const int dst0 = (wid << 6) * 16;          // wave-uniform; HW adds lane*16
  const int dst1 = (512 + (wid << 6)) * 16;

  auto stageA = [&](int t){
    const int sb = (t & 3) << 14;            // slot * 16384 B
    const size_t kb = (size_t)t << 6;        // t * 64 B along k
    gll16(srcA0 + kb, AsB + sb + dst0);
    gll16(srcA1 + kb, AsB + sb + dst1);
  };
  auto stageB = [&](int t){
    const int sb = (t & 3) << 14;
    const size_t kb = (size_t)t << 6;
    gll16(srcB0 + kb, BsB + sb + dst0);
    gll16(srcB1 + kb, BsB + sb + dst1);
  };

  f32x4 acc[8][4];
  const f32x4 z = {0.f, 0.f, 0.f, 0.f};
#pragma unroll
  for (int m = 0; m < 8; ++m)
#pragma unroll
    for (int n = 0; n < 4; ++n) acc[m][n] = z;

  // fragment ds_read offsets (ushort units); swizzled chunk lane-constant.
  const int cio  = (lo2 ^ lrh) << 3;
  const int aoff = (wm*64 + lrh)*64 + cio;
  const int boff = (wn*32 + lrh)*64 + cio;

  // prologue: slots 0,1 in flight (8 loads/thread)
  stageA(0); stageB(0); stageA(1); stageB(1);
  asm volatile("s_waitcnt vmcnt(4)" ::: "memory");   // slot 0 landed (mine)
  __builtin_amdgcn_s_barrier();                      // slot 0 landed (all)

  for (int t = 0; t < NT; ++t){
    const int s = t & 3;
    const ushort* Asl = (const ushort*)As + (size_t)s*8192;
    const ushort* Bsl = (const ushort*)Bs + (size_t)s*8192;
    const bool pre = (t + 2 < NT);

    // ---- phase 0: B-frags + A-frags m0-3, MFMA half m0-3 ----
    bf16x8 bfv[4], af0[4];
#pragma unroll
    for (int n = 0; n < 4; ++n)
      bfv[n] = *(const bf16x8*)&Bsl[boff + n*512];
#pragma unroll
    for (int m = 0; m < 4; ++m)
      af0[m] = *(const bf16x8*)&Asl[aoff + m*512];
    if (pre) stageA(t + 2);
    __builtin_amdgcn_s_barrier();
    __builtin_amdgcn_s_setprio(1);
#pragma unroll
    for (int m = 0; m < 4; ++m)
#pragma unroll
      for (int n = 0; n < 4; ++n)
        acc[m][n] = __builtin_amdgcn_mfma_f32_16x16x32_bf16(af0[m], bfv[n], acc[m][n], 0, 0, 0);
    __builtin_amdgcn_s_setprio(0);
    __builtin_amdgcn_s_barrier();

    // ---- phase 1: A-frags m4-7, MFMA half m4-7 (B-frags reused) ----
    bf16x8 af1[4];
#pragma unroll
    for (int m = 0; m < 4; ++m)
      af1[m] = *(const bf16x8*)&Asl[aoff + (m + 4)*512];
    if (pre) stageB(t + 2);
    __builtin_amdgcn_s_barrier();
    __builtin_amdgcn_s_setprio(1);
#pragma unroll
    for (int m = 0; m < 4; ++m)
#pragma unroll
      for (int n = 0; n < 4; ++n)
        acc[m + 4][n] = __builtin_amdgcn_mfma_f32_16x16x32_bf16(af1[m], bfv[n], acc[m + 4][n], 0, 0, 0);
    __builtin_amdgcn_s_setprio(0);

    // ---- slot tail: guarantee slot t+1 landed (counted; drains only at end) ----
    if (t < NT - 1){
      if (t + 2 < NT) asm volatile("s_waitcnt vmcnt(4)" ::: "memory");
      else            asm volatile("s_waitcnt vmcnt(0)" ::: "memory");
      __builtin_amdgcn_s_barrier();
    }
  }

  // ---------------- epilogue ----------------
  const int rbase = bm*256 + wm*128 + fq*4;
  const int cbase = bn*256 + wn*64 + lr;

  if (MODE == 0){
    if (bn >= 8){
      // V block: write transposed, VT[b][dv][l], contiguous ushort4 over l
#pragma unroll
      for (int m = 0; m < 8; ++m){
        int r0 = rbase + m*16;
        int b = r0 >> 11, l = r0 & 2047;
        ushort* vb = VTout + (size_t)b * 1024 * 2048;
#pragma unroll
        for (int n = 0; n < 4; ++n){
          int c = cbase + n*16;
          float bvv = bias[c];
          ushort4 u4;
          u4.x = f2bf(acc[m][n][0] + bvv);
          u4.y = f2bf(acc[m][n][1] + bvv);
          u4.z = f2bf(acc[m][n][2] + bvv);
          u4.w = f2bf(acc[m][n][3] + bvv);
          *(ushort4*)&vb[(size_t)(c - 2048)*2048 + l] = u4;
        }
      }
    } else {
      ushort* dst = Cb + (size_t)bz * sC;
#pragma unroll
      for (int m = 0; m < 8; ++m){
        int r0 = rbase + m*16;
#pragma unroll
        for (int n = 0; n < 4; ++n){
          int c = cbase + n*16;
          float bvv = bias[c];
#pragma unroll
          for (int i = 0; i < 4; ++i)
            dst[(size_t)(r0 + i)*ldc + c] = f2bf(acc[m][n][i] + bvv);
        }
      }
    }
  } else if (MODE == 1){
    ushort* dst = Cb + (size_t)bz * sC;
#pragma unroll
    for (int m = 0; m < 8; ++m){
      int r0 = rbase + m*16;
#pragma unroll
      for (int i = 0; i < 4; ++i){
        int r = r0 + i;
        float rs = 0.f;
#pragma unroll
        for (int n = 0; n < 4; ++n){
          float v = __expf(acc[m][n][i] * scale);
          dst[(size_t)r*ldc + cbase + n*16] = f2bf(v);
          rs += v;            // f32 sum from f32 exp values (NOT bf16-rounded)
        }
        rs += __shfl_xor(rs, 1);
        rs += __shfl_xor(rs, 2);
        rs += __shfl_xor(rs, 4);
        rs += __shfl_xor(rs, 8);
        if (lr == 0)
          partial[((size_t)bz*Mrows + r)*nch + (bn*4 + wn)] = rs;  // single writer
      }
    }
  } else {
    // denom for this block's 256 rows, computed in-block (deterministic:
    // fixed-order f32 sum of the 32 partials; same value in all 4 bn-blocks)
    if (tid < 256){
      int r = bm*256 + tid;
      const float* p = partial + ((size_t)bz*Mrows + r)*32;
      float ssum = 0.f;
#pragma unroll
      for (int j = 0; j < 32; ++j) ssum += p[j];
      dnls[tid] = ssum - (float)(Mrows - alen[bz]);
    }
    __syncthreads();
    float* dst = Cf + (size_t)bz * sC;
#pragma unroll
    for (int m = 0; m < 8; ++m){
      int r0 = rbase + m*16;
#pragma unroll
      for (int i = 0; i < 4; ++i){
        int r = r0 + i;
        float inv = 1.0f / dnls[r - bm*256];
#pragma unroll
        for (int n = 0; n < 4; ++n)
          dst[(size_t)r*ldc + cbase + n*16] = acc[m][n][i] * inv;
      }
    }
  }
}

// ---------------------------------------------------------------------------

__global__ void cvt_f32_bf16(const float* __restrict__ in, ushort* __restrict__ out, long n4){
  long i = (long)blockIdx.x*blockDim.x + threadIdx.x;
  if (i >= n4) return;
  float4 f = ((const float4*)in)[i];
  ushort4 u;
  u.x = f2bf(f.x); u.y = f2bf(f.y); u.z = f2bf(f.z); u.w = f2bf(f.w);
  ((ushort4*)out)[i] = u;
}

// merged: out[z][C,R] = in_z[R,C]^T with f32->bf16 convert. block (32,8), z<3
__global__ __launch_bounds__(256) void transpose_w3(
    const float* __restrict__ Wq, const float* __restrict__ Wk,
    const float* __restrict__ Wv, ushort* __restrict__ out, int R, int C){
  __shared__ ushort t[32][33];
  int zz = blockIdx.z;
  const float* in = (zz == 0) ? Wq : (zz == 1 ? Wk : Wv);
  ushort* o = out + (size_t)zz * R * C;
  int tx = threadIdx.x, ty = threadIdx.y;
  int c0 = blockIdx.x*32, r0 = blockIdx.y*32;
#pragma unroll
  for (int i = 0; i < 4; i++)
    t[ty + i*8][tx] = f2bf(in[(size_t)(r0 + ty + i*8)*C + c0 + tx]);
  __syncthreads();
#pragma unroll
  for (int i = 0; i < 4; i++)
    o[(size_t)(c0 + ty + i*8)*R + r0 + tx] = t[tx][ty + i*8];
}

__global__ void pack_bias(const float* __restrict__ q, const float* __restrict__ k,
                          const float* __restrict__ v, float* __restrict__ o){
  int i = blockIdx.x*blockDim.x + threadIdx.x;   // 3072
  o[i] = (i < 1024) ? q[i] : (i < 2048 ? k[i-1024] : v[i-2048]);
}

// ---------------------------------------------------------------------------

extern "C" void kernel_launch(void* const* d_in, const int* in_sizes, int n_in,
                              void* d_out, int out_size, void* d_ws, size_t ws_size,
                              hipStream_t stream){
  const int B = 8, L = 2048, D = 1024, DK = 1024, DV = 1024;
  const float scale = 0.03125f;  // 1/sqrt(1024)

  const float* x  = (const float*)d_in[0];
  const int* alen = (const int*)d_in[1];
  const float* Wq = (const float*)d_in[2];
  const float* bq = (const float*)d_in[3];
  const float* Wk = (const float*)d_in[4];
  const float* bk = (const float*)d_in[5];
  const float* Wv = (const float*)d_in[6];
  const float* bv = (const float*)d_in[7];
  float* out = (float*)d_out;

  char* ws = (char*)d_ws;
  size_t off = 0;
  auto alloc = [&](size_t bytes) -> void* {
    void* p = ws + off;
    off += (bytes + 255) & ~(size_t)255;
    return p;
  };
  ushort* xb     = (ushort*)alloc((size_t)B*L*D*2);        // 32 MB
  ushort* wqkvT  = (ushort*)alloc((size_t)3*DK*D*2);       // 6 MB
  float*  bqkv   = (float*)alloc((size_t)3*DK*4);
  ushort* QK     = (ushort*)alloc((size_t)B*L*2*DK*2);     // 67 MB (Q|K packed rows)
  ushort* VTb    = (ushort*)alloc((size_t)B*DV*L*2);       // 32 MB (V transposed)
  ushort* S      = (ushort*)alloc((size_t)B*L*L*2);        // 64 MB
  float* partial = (float*)alloc((size_t)B*L*32*4);        // 2 MB
  if (off > ws_size) return;

  // 1. x -> bf16
  long n4 = (long)B*L*D/4;
  cvt_f32_bf16<<<dim3((unsigned)((n4 + 255)/256)), 256, 0, stream>>>(x, xb, n4);

  // 2. packed W^T bf16 [3072][1024] (one launch) + packed bias
  transpose_w3<<<dim3(DK/32, D/32, 3), dim3(32, 8), 0, stream>>>(Wq, Wk, Wv, wqkvT, D, DK);
  pack_bias<<<dim3(12), 256, 0, stream>>>(bq, bk, bv, bqkv);

  // 3. fused QKV projection: Q,K -> QK[B*L, 2048]; V -> VTb transposed
  gemm256<0><<<dim3(64*12), 512, 0, stream>>>(
      xb, wqkvT, bqkv, QK, nullptr, VTb, 64, 12, D, D, D, 2*DK,
      0, 0, 0, 0.f, nullptr, nullptr, 0, 0);

  // 4. scores: S = exp(scale * Q @ K^T), f32 partial row sums
  gemm256<1><<<dim3(8*8*8), 512, 0, stream>>>(
      QK /*Q*/, QK + DK /*K*/, nullptr, S, nullptr, nullptr, 8, 8, DK,
      2*DK, 2*DK, L,
      (size_t)L*2*DK, (size_t)L*2*DK, (size_t)L*L, scale, partial, nullptr, L, 32);

  // 5. out = (S @ V) / denom   (denom computed in-block from partials)
  gemm256<2><<<dim3(8*4*8), 512, 0, stream>>>(
      S, VTb, nullptr, nullptr, out, nullptr, 8, 4, L, L, L, DV,
      (size_t)L*L, (size_t)DV*L, (size_t)L*DV, 1.f, partial, alen, L, 0);
}